// Round 1
// baseline (1661.431 us; speedup 1.0000x reference)
//
#include <hip/hip_runtime.h>
#include <hip/hip_bf16.h>
#include <math.h>

#define BDIM 384
#define HEADS 8
#define HD 48
#define HID 1536
#define BB 32
#define HH 56
#define WW 56
#define NN 3136            // 56*56
#define MTOT (BB*NN)       // 100352
#define TPW 8              // tokens per wave in cpe/ln kernels

typedef unsigned short ushort_t;
typedef __attribute__((ext_vector_type(8))) short short8;   // 8 x bf16 (4 VGPRs)
typedef __attribute__((ext_vector_type(4))) float floatx4;  // 4 x f32 acc

__device__ inline float bf2f(ushort_t u){ return __uint_as_float(((unsigned)u)<<16); }
__device__ inline ushort_t f2bf(float f){
  unsigned u = __float_as_uint(f);
  u += 0x7fff + ((u>>16)&1);   // round-to-nearest-even
  return (ushort_t)(u>>16);
}

// async global->LDS, 16B per lane; lds dest = wave-uniform base + lane*16
__device__ inline void async_ld16(const void* g, void* l){
  __builtin_amdgcn_global_load_lds((const __attribute__((address_space(1))) void*)g,
                                   (__attribute__((address_space(3))) void*)l, 16, 0, 0);
}

// ---------------- weight fp32 -> bf16 ----------------
__global__ void convert_bf16_kernel(const float* __restrict__ in, ushort_t* __restrict__ out, int n){
  int i = blockIdx.x*256 + threadIdx.x;
  if (i < n) out[i] = f2bf(in[i]);
}

// ---------------- CPE depthwise 3x3 conv + residual + LN1 (wave-per-token, no barriers) ----------------
// block 256 = 4 waves; each wave does TPW consecutive tokens; lane owns channels p*64+lane
__global__ __launch_bounds__(256)
void cpe_ln1_kernel(const float* __restrict__ x, const float* __restrict__ cw,
                    const float* __restrict__ cb, const float* __restrict__ lw,
                    const float* __restrict__ lb, float* __restrict__ x1out,
                    ushort_t* __restrict__ cur){
  int lane = threadIdx.x & 63, wave = threadIdx.x >> 6;
  size_t base = ((size_t)blockIdx.x*4 + wave) * TPW;
  float wreg[6][9], cbr[6], lwr[6], lbr[6];
  #pragma unroll
  for (int p = 0; p < 6; ++p){
    int c = p*64 + lane;
    cbr[p] = cb[c]; lwr[p] = lw[c]; lbr[p] = lb[c];
    #pragma unroll
    for (int j = 0; j < 9; ++j) wreg[p][j] = cw[c*9+j];
  }
  for (int ti = 0; ti < TPW; ++ti){
    size_t bn = base + ti;
    int b = (int)(bn / NN), n = (int)(bn % NN);
    int h = n / WW, w = n % WW;
    const float* xb = x + ((size_t)b*NN)*BDIM;
    float conv[6];
    #pragma unroll
    for (int p = 0; p < 6; ++p) conv[p] = cbr[p];
    #pragma unroll
    for (int dh = -1; dh <= 1; ++dh){
      int hh = h + dh; if ((unsigned)hh >= HH) continue;
      #pragma unroll
      for (int dw = -1; dw <= 1; ++dw){
        int w2 = w + dw; if ((unsigned)w2 >= WW) continue;
        const float* src = xb + (size_t)(hh*WW + w2)*BDIM + lane;
        int j = (dh+1)*3 + (dw+1);
        #pragma unroll
        for (int p = 0; p < 6; ++p) conv[p] += src[p*64] * wreg[p][j];
      }
    }
    const float* xc = xb + (size_t)n*BDIM + lane;
    float x1[6], s = 0.f, q = 0.f;
    #pragma unroll
    for (int p = 0; p < 6; ++p){
      x1[p] = xc[p*64] + conv[p];
      s += x1[p]; q += x1[p]*x1[p];
    }
    #pragma unroll
    for (int off = 32; off; off >>= 1){
      s += __shfl_xor(s, off);
      q += __shfl_xor(q, off);
    }
    float mean = s*(1.f/384.f);
    float rstd = rsqrtf(q*(1.f/384.f) - mean*mean + 1e-5f);
    float* xo = x1out + bn*BDIM + lane;
    ushort_t* co = cur + bn*BDIM + lane;
    #pragma unroll
    for (int p = 0; p < 6; ++p){
      xo[p*64] = x1[p];
      co[p*64] = f2bf((x1[p]-mean)*rstd*lwr[p] + lbr[p]);
    }
  }
}

// ---------------- plain LN (wave-per-token, no barriers) ----------------
__global__ __launch_bounds__(256)
void ln_kernel(const float* __restrict__ xin, const float* __restrict__ lw,
               const float* __restrict__ lb, ushort_t* __restrict__ outb){
  int lane = threadIdx.x & 63, wave = threadIdx.x >> 6;
  size_t base = ((size_t)blockIdx.x*4 + wave) * TPW;
  float lwr[6], lbr[6];
  #pragma unroll
  for (int p = 0; p < 6; ++p){ lwr[p] = lw[p*64+lane]; lbr[p] = lb[p*64+lane]; }
  for (int ti = 0; ti < TPW; ++ti){
    size_t bn = base + ti;
    const float* xi = xin + bn*BDIM + lane;
    float v[6], s = 0.f, q = 0.f;
    #pragma unroll
    for (int p = 0; p < 6; ++p){
      v[p] = xi[p*64];
      s += v[p]; q += v[p]*v[p];
    }
    #pragma unroll
    for (int off = 32; off; off >>= 1){
      s += __shfl_xor(s, off);
      q += __shfl_xor(q, off);
    }
    float mean = s*(1.f/384.f);
    float rstd = rsqrtf(q*(1.f/384.f) - mean*mean + 1e-5f);
    ushort_t* oo = outb + bn*BDIM + lane;
    #pragma unroll
    for (int p = 0; p < 6; ++p) oo[p*64] = f2bf((v[p]-mean)*rstd*lwr[p] + lbr[p]);
  }
}

// ---------------- bf16 MFMA GEMM, double-buffered LDS + early async staging ----------------
// BM=BN=128, BK=32; 256 threads = 4 waves in 2x2; each wave: 4x4 tiles of 16x16.
// 2-phase pipeline (T3 minimum): issue next-tile global_load_lds BEFORE current tile's
// ds_read+MFMA, single __syncthreads() per K-step -> vmcnt(0) drain lands after MFMA,
// so HBM latency hides under compute instead of being exposed every iteration.
template<int EP>
__global__ __launch_bounds__(256)
void gemm_kernel(const ushort_t* __restrict__ A, const ushort_t* __restrict__ Bw,
                 const float* __restrict__ bias, const float* __restrict__ resid,
                 void* __restrict__ outp, int Ncols, int K){
  __shared__ __align__(16) ushort_t As[2][128*32];
  __shared__ __align__(16) ushort_t Bs[2][128*32];
  const int t = threadIdx.x;
  const int lane = t & 63, wave = t >> 6;
  const int wm = wave >> 1, wn = wave & 1;
  const size_t m0 = (size_t)blockIdx.y * 128;
  const int n0 = blockIdx.x * 128;
  const int lrow = lane & 15, lk = (lane >> 4) << 3;
  floatx4 zero4 = {0.f, 0.f, 0.f, 0.f};
  floatx4 acc[4][4];
  #pragma unroll
  for (int i = 0; i < 4; ++i)
    #pragma unroll
    for (int j = 0; j < 4; ++j) acc[i][j] = zero4;

  // stage one BK=32 tile pair into buffer `buf`; lane-linear dest matches idx-linear src
  auto stage = [&](int buf, int k0){
    #pragma unroll
    for (int l = 0; l < 2; ++l){
      int idx = t + l*256;              // 0..511
      int row = idx >> 2;               // 0..127
      int ko  = (idx & 3) << 3;         // 0,8,16,24
      int lbase = (l*256 + wave*64) * 8;  // wave-uniform LDS elem base; lane lands at +lane*8
      async_ld16(&A[(m0 + row)*K + (k0 + ko)], &As[buf][lbase]);
      async_ld16(&Bw[(size_t)(n0 + row)*K + (k0 + ko)], &Bs[buf][lbase]);
    }
  };

  stage(0, 0);
  __syncthreads();          // vmcnt(0) drain: buffer 0 ready
  int cur = 0;
  for (int k0 = 0; k0 < K; k0 += 32){
    if (k0 + 32 < K) stage(cur ^ 1, k0 + 32);   // issue next tile's loads FIRST
    short8 af[4], bfr[4];
    #pragma unroll
    for (int i = 0; i < 4; ++i) af[i]  = *(const short8*)&As[cur][(wm*64 + i*16 + lrow)*32 + lk];
    #pragma unroll
    for (int j = 0; j < 4; ++j) bfr[j] = *(const short8*)&Bs[cur][(wn*64 + j*16 + lrow)*32 + lk];
    #pragma unroll
    for (int i = 0; i < 4; ++i)
      #pragma unroll
      for (int j = 0; j < 4; ++j)
        acc[i][j] = __builtin_amdgcn_mfma_f32_16x16x32_bf16(af[i], bfr[j], acc[i][j], 0, 0, 0);
    if (k0 + 32 < K){
      __syncthreads();      // drains next-tile vmcnt AFTER MFMA; all waves done reading cur
      cur ^= 1;
    }
  }

  const int quad = lane >> 4;
  #pragma unroll
  for (int i = 0; i < 4; ++i){
    #pragma unroll
    for (int j = 0; j < 4; ++j){
      int gn = n0 + wn*64 + j*16 + lrow;
      float bv = bias[gn];
      #pragma unroll
      for (int r = 0; r < 4; ++r){
        size_t gm = m0 + wm*64 + i*16 + quad*4 + r;
        float v = acc[i][j][r] + bv;
        if constexpr (EP == 0){
          if (gn < 768) v = fmaxf(v, 0.f);
          ((ushort_t*)outp)[gm*Ncols + gn] = f2bf(v);
        } else if constexpr (EP == 1){
          v = 0.5f*v*(1.f + erff(v*0.70710678118f));
          ((ushort_t*)outp)[gm*Ncols + gn] = f2bf(v);
        } else {
          ((float*)outp)[gm*Ncols + gn] = v + resid[gm*Ncols + gn];
        }
      }
    }
  }
}

// ---------------- kv via MFMA (unchanged) ----------------
__global__ __launch_bounds__(256)
void kv_mfma_kernel(const ushort_t* __restrict__ qkv, float* __restrict__ kvT_out,
                    float* __restrict__ ksum_out){
  __shared__ __align__(16) ushort_t smem[2*48*72];   // kT [48][72], vT [48][72]
  ushort_t* kT = smem;
  ushort_t* vT = smem + 48*72;
  int bh = blockIdx.x, b = bh >> 3, h = bh & 7;
  int chunk = blockIdx.y;
  int t = threadIdx.x, lane = t & 63, wave = t >> 6;
  int lrow = lane & 15, quad = lane >> 4;
  const ushort_t* kb = qkv + (size_t)b*NN*1152 + 384 + h*48;
  const ushort_t* vb = kb + 384;
  floatx4 acc[9];
  #pragma unroll
  for (int i = 0; i < 9; ++i) acc[i] = (floatx4){0.f,0.f,0.f,0.f};
  float ks = 0.f;

  for (int s = 0; s < 7; ++s){
    int n0 = chunk*448 + s*64;
    #pragma unroll
    for (int p = 0; p < 3; ++p){
      int u = t + p*256;              // 0..767
      int arr = u / 384;              // 0=k, 1=v
      int r = u - arr*384;
      int d8 = r >> 6;                // 0..5
      int nl = r & 63;
      const ushort_t* src = (arr ? vb : kb) + (size_t)(n0 + nl)*1152 + d8*8;
      ushort_t* dst = arr ? vT : kT;
      uint4 val = *(const uint4*)src;
      ushort_t tmp[8];
      *(uint4*)tmp = val;
      #pragma unroll
      for (int j = 0; j < 8; ++j) dst[(d8*8 + j)*72 + nl] = tmp[j];
    }
    __syncthreads();
    if ((wave >> 1) == (s & 1)){
      int kloc = (wave & 1) * 32;
      short8 af[3], bfv[3];
      #pragma unroll
      for (int i = 0; i < 3; ++i) af[i]  = *(const short8*)&kT[(i*16 + lrow)*72 + kloc + quad*8];
      #pragma unroll
      for (int j = 0; j < 3; ++j) bfv[j] = *(const short8*)&vT[(j*16 + lrow)*72 + kloc + quad*8];
      #pragma unroll
      for (int i = 0; i < 3; ++i)
        #pragma unroll
        for (int j = 0; j < 3; ++j)
          acc[i*3+j] = __builtin_amdgcn_mfma_f32_16x16x32_bf16(af[i], bfv[j], acc[i*3+j], 0, 0, 0);
    }
    if (wave == 3 && lane < 48){
      float s2 = 0.f;
      #pragma unroll
      for (int q8 = 0; q8 < 8; ++q8){
        short8 kk = *(const short8*)&kT[lane*72 + q8*8];
        #pragma unroll
        for (int j = 0; j < 8; ++j) s2 += bf2f((ushort_t)kk[j]);
      }
      ks += s2;
    }
    __syncthreads();
  }

  float* F = (float*)smem;
  #define DUMP(W) if (wave == (W)){ _Pragma("unroll") for (int ti = 0; ti < 9; ++ti){ _Pragma("unroll") for (int r = 0; r < 4; ++r){ int d = (ti/3)*16 + quad*4 + r, e = (ti%3)*16 + lrow; F[d*48 + e] = acc[ti][r]; } } }
  #define ADDF(W) if (wave == (W)){ _Pragma("unroll") for (int ti = 0; ti < 9; ++ti){ _Pragma("unroll") for (int r = 0; r < 4; ++r){ int d = (ti/3)*16 + quad*4 + r, e = (ti%3)*16 + lrow; acc[ti][r] += F[d*48 + e]; } } }
  DUMP(1) __syncthreads(); ADDF(0) __syncthreads();
  DUMP(3) __syncthreads(); ADDF(2) __syncthreads();
  DUMP(2) __syncthreads(); ADDF(0) __syncthreads();
  #undef DUMP
  #undef ADDF
  if (wave == 0){
    #pragma unroll
    for (int ti = 0; ti < 9; ++ti){
      #pragma unroll
      for (int r = 0; r < 4; ++r){
        int d = (ti/3)*16 + quad*4 + r, e = (ti%3)*16 + lrow;
        atomicAdd(&kvT_out[(size_t)bh*2304 + e*48 + d], acc[ti][r]);
      }
    }
  }
  if (wave == 3 && lane < 48) atomicAdd(&ksum_out[bh*48 + lane], ks);
}

// ---------------- attn via MFMA (unchanged) ----------------
__global__ __launch_bounds__(256)
void attn_mfma_kernel(const ushort_t* __restrict__ qkv, const float* __restrict__ kvT,
                      const float* __restrict__ ksum, const float* __restrict__ temp,
                      ushort_t* __restrict__ attn_out){
  __shared__ __align__(16) ushort_t Bs[64*72];
  int bh = blockIdx.x, b = bh >> 3, h = bh & 7;
  int t = threadIdx.x, lane = t & 63, wave = t >> 6;
  int lrow = lane & 15, quad = lane >> 4;
  float tf = temp[h];
  for (int u = t; u < 64*72; u += 256){
    int col = u / 72, d = u - col*72;
    float v = 0.f;
    if (d < 48){
      if (col < 48) v = kvT[(size_t)bh*2304 + col*48 + d] * tf;
      else if (col == 48) v = ksum[bh*48 + d];
    }
    Bs[u] = f2bf(v);
  }
  __syncthreads();
  short8 bfv[4][2];
  #pragma unroll
  for (int j = 0; j < 4; ++j)
    #pragma unroll
    for (int s = 0; s < 2; ++s)
      bfv[j][s] = *(const short8*)&Bs[(j*16 + lrow)*72 + s*32 + quad*8];

  const ushort_t* qb = qkv + (size_t)b*NN*1152 + h*48;
  int n0 = blockIdx.y*256 + wave*64;
  floatx4 acc[4][4];
  #pragma unroll
  for (int i = 0; i < 4; ++i)
    #pragma unroll
    for (int j = 0; j < 4; ++j) acc[i][j] = (floatx4){0.f,0.f,0.f,0.f};

  #pragma unroll
  for (int i = 0; i < 4; ++i){
    int nrow = n0 + i*16 + lrow;
    #pragma unroll
    for (int s = 0; s < 2; ++s){
      short8 af = *(const short8*)&qb[(size_t)nrow*1152 + s*32 + quad*8];
      #pragma unroll
      for (int j = 0; j < 4; ++j)
        acc[i][j] = __builtin_amdgcn_mfma_f32_16x16x32_bf16(af, bfv[j][s], acc[i][j], 0, 0, 0);
    }
  }

  ushort_t* ob = attn_out + (size_t)b*NN*BDIM + h*48;
  #pragma unroll
  for (int i = 0; i < 4; ++i){
    #pragma unroll
    for (int r = 0; r < 4; ++r){
      float den = __shfl(acc[i][3][r], quad*16);
      den = fmaxf(den, 100.f);
      int nrow = n0 + i*16 + quad*4 + r;
      if (nrow < NN){
        #pragma unroll
        for (int j = 0; j < 3; ++j)
          ob[(size_t)nrow*BDIM + j*16 + lrow] = f2bf(acc[i][j][r] / den);
      }
    }
  }
}

extern "C" void kernel_launch(void* const* d_in, const int* in_sizes, int n_in,
                              void* d_out, int out_size, void* d_ws, size_t ws_size,
                              hipStream_t stream){
  const float* x     = (const float*)d_in[0];
  const float* cpe_w = (const float*)d_in[3];
  const float* cpe_b = (const float*)d_in[4];
  const float* ln1_w = (const float*)d_in[5];
  const float* ln1_b = (const float*)d_in[6];
  const float* qkv_w = (const float*)d_in[7];
  const float* qkv_b = (const float*)d_in[8];
  const float* temp  = (const float*)d_in[9];
  const float* proj_w= (const float*)d_in[10];
  const float* proj_b= (const float*)d_in[11];
  const float* ln2_w = (const float*)d_in[12];
  const float* ln2_b = (const float*)d_in[13];
  const float* fc1_w = (const float*)d_in[14];
  const float* fc1_b = (const float*)d_in[15];
  const float* fc2_w = (const float*)d_in[16];
  const float* fc2_b = (const float*)d_in[17];
  float* out = (float*)d_out;

  char* ws = (char*)d_ws;
  size_t off = 0;
  auto alloc = [&](size_t bytes) -> void* {
    void* p = ws + off;
    off += (bytes + 255) & ~(size_t)255;
    return p;
  };
  ushort_t* cur  = (ushort_t*)alloc((size_t)MTOT*BDIM*2);
  ushort_t* big  = (ushort_t*)alloc((size_t)MTOT*HID*2);
  float*    kvT  = (float*)   alloc((size_t)BB*HEADS*HD*HD*4);
  float*    ksum = (float*)   alloc((size_t)BB*HEADS*HD*4);
  ushort_t* wq = (ushort_t*)alloc((size_t)3*BDIM*BDIM*2);
  ushort_t* wp = (ushort_t*)alloc((size_t)BDIM*BDIM*2);
  ushort_t* w1 = (ushort_t*)alloc((size_t)HID*BDIM*2);
  ushort_t* w2 = (ushort_t*)alloc((size_t)BDIM*HID*2);

  convert_bf16_kernel<<<(3*BDIM*BDIM + 255)/256, 256, 0, stream>>>(qkv_w, wq, 3*BDIM*BDIM);
  convert_bf16_kernel<<<(BDIM*BDIM + 255)/256, 256, 0, stream>>>(proj_w, wp, BDIM*BDIM);
  convert_bf16_kernel<<<(HID*BDIM + 255)/256, 256, 0, stream>>>(fc1_w, w1, HID*BDIM);
  convert_bf16_kernel<<<(BDIM*HID + 255)/256, 256, 0, stream>>>(fc2_w, w2, BDIM*HID);

  hipMemsetAsync(kvT, 0, (size_t)BB*HEADS*HD*HD*4, stream);
  hipMemsetAsync(ksum, 0, (size_t)BB*HEADS*HD*4, stream);

  cpe_ln1_kernel<<<MTOT/(4*TPW), 256, 0, stream>>>(x, cpe_w, cpe_b, ln1_w, ln1_b, out, cur);
  gemm_kernel<0><<<dim3(9, 784), 256, 0, stream>>>(cur, wq, qkv_b, nullptr, big, 1152, BDIM);
  kv_mfma_kernel<<<dim3(BB*HEADS, 7), 256, 0, stream>>>(big, kvT, ksum);
  attn_mfma_kernel<<<dim3(BB*HEADS, 13), 256, 0, stream>>>(big, kvT, ksum, temp, cur);
  gemm_kernel<2><<<dim3(3, 784), 256, 0, stream>>>(cur, wp, proj_b, out, out, BDIM, BDIM);
  ln_kernel<<<MTOT/(4*TPW), 256, 0, stream>>>(out, ln2_w, ln2_b, cur);
  gemm_kernel<1><<<dim3(12, 784), 256, 0, stream>>>(cur, w1, fc1_b, nullptr, big, HID, BDIM);
  gemm_kernel<2><<<dim3(3, 784), 256, 0, stream>>>(big, w2, fc2_b, out, out, BDIM, HID);
}

// Round 3
// 1474.244 us; speedup vs baseline: 1.1270x; 1.1270x over previous
//
#include <hip/hip_runtime.h>
#include <hip/hip_bf16.h>
#include <math.h>

#define BDIM 384
#define HEADS 8
#define HD 48
#define HID 1536
#define BB 32
#define HH 56
#define WW 56
#define NN 3136            // 56*56
#define MTOT (BB*NN)       // 100352
#define TPW 8              // tokens per wave in cpe/ln kernels

typedef unsigned short ushort_t;
typedef __attribute__((ext_vector_type(8))) short short8;   // 8 x bf16 (4 VGPRs)
typedef __attribute__((ext_vector_type(4))) float floatx4;  // 4 x f32 acc

__device__ inline float bf2f(ushort_t u){ return __uint_as_float(((unsigned)u)<<16); }
__device__ inline ushort_t f2bf(float f){
  unsigned u = __float_as_uint(f);
  u += 0x7fff + ((u>>16)&1);   // round-to-nearest-even
  return (ushort_t)(u>>16);
}

// async global->LDS, 16B per lane; lds dest = wave-uniform base + lane*16
__device__ inline void async_ld16(const void* g, void* l){
  __builtin_amdgcn_global_load_lds((const __attribute__((address_space(1))) void*)g,
                                   (__attribute__((address_space(3))) void*)l, 16, 0, 0);
}

// ---------------- weight fp32 -> bf16 ----------------
__global__ void convert_bf16_kernel(const float* __restrict__ in, ushort_t* __restrict__ out, int n){
  int i = blockIdx.x*256 + threadIdx.x;
  if (i < n) out[i] = f2bf(in[i]);
}

// ---------------- CPE depthwise 3x3 conv + residual + LN1 (wave-per-token, no barriers) ----------------
// block 256 = 4 waves; each wave does TPW consecutive tokens; lane owns channels p*64+lane
__global__ __launch_bounds__(256)
void cpe_ln1_kernel(const float* __restrict__ x, const float* __restrict__ cw,
                    const float* __restrict__ cb, const float* __restrict__ lw,
                    const float* __restrict__ lb, float* __restrict__ x1out,
                    ushort_t* __restrict__ cur){
  int lane = threadIdx.x & 63, wave = threadIdx.x >> 6;
  size_t base = ((size_t)blockIdx.x*4 + wave) * TPW;
  float wreg[6][9], cbr[6], lwr[6], lbr[6];
  #pragma unroll
  for (int p = 0; p < 6; ++p){
    int c = p*64 + lane;
    cbr[p] = cb[c]; lwr[p] = lw[c]; lbr[p] = lb[c];
    #pragma unroll
    for (int j = 0; j < 9; ++j) wreg[p][j] = cw[c*9+j];
  }
  for (int ti = 0; ti < TPW; ++ti){
    size_t bn = base + ti;
    int b = (int)(bn / NN), n = (int)(bn % NN);
    int h = n / WW, w = n % WW;
    const float* xb = x + ((size_t)b*NN)*BDIM;
    float conv[6];
    #pragma unroll
    for (int p = 0; p < 6; ++p) conv[p] = cbr[p];
    #pragma unroll
    for (int dh = -1; dh <= 1; ++dh){
      int hh = h + dh; if ((unsigned)hh >= HH) continue;
      #pragma unroll
      for (int dw = -1; dw <= 1; ++dw){
        int w2 = w + dw; if ((unsigned)w2 >= WW) continue;
        const float* src = xb + (size_t)(hh*WW + w2)*BDIM + lane;
        int j = (dh+1)*3 + (dw+1);
        #pragma unroll
        for (int p = 0; p < 6; ++p) conv[p] += src[p*64] * wreg[p][j];
      }
    }
    const float* xc = xb + (size_t)n*BDIM + lane;
    float x1[6], s = 0.f, q = 0.f;
    #pragma unroll
    for (int p = 0; p < 6; ++p){
      x1[p] = xc[p*64] + conv[p];
      s += x1[p]; q += x1[p]*x1[p];
    }
    #pragma unroll
    for (int off = 32; off; off >>= 1){
      s += __shfl_xor(s, off);
      q += __shfl_xor(q, off);
    }
    float mean = s*(1.f/384.f);
    float rstd = rsqrtf(q*(1.f/384.f) - mean*mean + 1e-5f);
    float* xo = x1out + bn*BDIM + lane;
    ushort_t* co = cur + bn*BDIM + lane;
    #pragma unroll
    for (int p = 0; p < 6; ++p){
      xo[p*64] = x1[p];
      co[p*64] = f2bf((x1[p]-mean)*rstd*lwr[p] + lbr[p]);
    }
  }
}

// ---------------- plain LN (wave-per-token, no barriers) ----------------
__global__ __launch_bounds__(256)
void ln_kernel(const float* __restrict__ xin, const float* __restrict__ lw,
               const float* __restrict__ lb, ushort_t* __restrict__ outb){
  int lane = threadIdx.x & 63, wave = threadIdx.x >> 6;
  size_t base = ((size_t)blockIdx.x*4 + wave) * TPW;
  float lwr[6], lbr[6];
  #pragma unroll
  for (int p = 0; p < 6; ++p){ lwr[p] = lw[p*64+lane]; lbr[p] = lb[p*64+lane]; }
  for (int ti = 0; ti < TPW; ++ti){
    size_t bn = base + ti;
    const float* xi = xin + bn*BDIM + lane;
    float v[6], s = 0.f, q = 0.f;
    #pragma unroll
    for (int p = 0; p < 6; ++p){
      v[p] = xi[p*64];
      s += v[p]; q += v[p]*v[p];
    }
    #pragma unroll
    for (int off = 32; off; off >>= 1){
      s += __shfl_xor(s, off);
      q += __shfl_xor(q, off);
    }
    float mean = s*(1.f/384.f);
    float rstd = rsqrtf(q*(1.f/384.f) - mean*mean + 1e-5f);
    ushort_t* oo = outb + bn*BDIM + lane;
    #pragma unroll
    for (int p = 0; p < 6; ++p) oo[p*64] = f2bf((v[p]-mean)*rstd*lwr[p] + lbr[p]);
  }
}

// ---------------- bf16 MFMA GEMM with async global->LDS staging ----------------
// BM=BN=128, BK=32; 256 threads = 4 waves in 2x2; each wave: 4x4 tiles of 16x16.
// Single-buffer 2-barrier structure (proven round-0 baseline) + bijective XCD
// swizzle (T1/m204): each XCD gets a contiguous row-major range of blocks, so
// all column-blocks sharing an A row-panel land on ONE XCD -> A re-reads become
// L2-local instead of L3, shortening the per-iteration barrier-drain latency.
template<int EP>
__global__ __launch_bounds__(256)
void gemm_kernel(const ushort_t* __restrict__ A, const ushort_t* __restrict__ Bw,
                 const float* __restrict__ bias, const float* __restrict__ resid,
                 void* __restrict__ outp, int Ncols, int K){
  __shared__ __align__(16) ushort_t As[128*32];
  __shared__ __align__(16) ushort_t Bs[128*32];
  const int t = threadIdx.x;
  const int lane = t & 63, wave = t >> 6;
  const int wm = wave >> 1, wn = wave & 1;

  // bijective XCD-aware remap (m204). All our grids have nwg % 8 == 0.
  const int gx = gridDim.x;
  const int nwg = gx * gridDim.y;
  int orig = blockIdx.y * gx + blockIdx.x;
  int qn = nwg >> 3, rn = nwg & 7;
  int xcd = orig & 7, pos = orig >> 3;
  int wg = (xcd < rn ? xcd*(qn+1) : rn*(qn+1) + (xcd-rn)*qn) + pos;
  int bx = wg % gx;
  int by = wg / gx;

  const size_t m0 = (size_t)by * 128;
  const int n0 = bx * 128;
  const int lrow = lane & 15, lk = (lane >> 4) << 3;
  floatx4 zero4 = {0.f, 0.f, 0.f, 0.f};
  floatx4 acc[4][4];
  #pragma unroll
  for (int i = 0; i < 4; ++i)
    #pragma unroll
    for (int j = 0; j < 4; ++j) acc[i][j] = zero4;

  for (int k0 = 0; k0 < K; k0 += 32){
    #pragma unroll
    for (int l = 0; l < 2; ++l){
      int idx = t + l*256;              // 0..511
      int row = idx >> 2;               // 0..127
      int ko  = (idx & 3) << 3;         // 0,8,16,24
      int lbase = (l*256 + wave*64) * 8;  // wave-uniform LDS elem base; lane lands at +lane*8
      async_ld16(&A[(m0 + row)*K + (k0 + ko)], &As[lbase]);
      async_ld16(&Bw[(size_t)(n0 + row)*K + (k0 + ko)], &Bs[lbase]);
    }
    __syncthreads();
    short8 af[4], bfr[4];
    #pragma unroll
    for (int i = 0; i < 4; ++i) af[i]  = *(const short8*)&As[(wm*64 + i*16 + lrow)*32 + lk];
    #pragma unroll
    for (int j = 0; j < 4; ++j) bfr[j] = *(const short8*)&Bs[(wn*64 + j*16 + lrow)*32 + lk];
    #pragma unroll
    for (int i = 0; i < 4; ++i)
      #pragma unroll
      for (int j = 0; j < 4; ++j)
        acc[i][j] = __builtin_amdgcn_mfma_f32_16x16x32_bf16(af[i], bfr[j], acc[i][j], 0, 0, 0);
    __syncthreads();
  }

  const int quad = lane >> 4;
  #pragma unroll
  for (int i = 0; i < 4; ++i){
    #pragma unroll
    for (int j = 0; j < 4; ++j){
      int gn = n0 + wn*64 + j*16 + lrow;
      float bv = bias[gn];
      #pragma unroll
      for (int r = 0; r < 4; ++r){
        size_t gm = m0 + wm*64 + i*16 + quad*4 + r;
        float v = acc[i][j][r] + bv;
        if constexpr (EP == 0){
          if (gn < 768) v = fmaxf(v, 0.f);
          ((ushort_t*)outp)[gm*Ncols + gn] = f2bf(v);
        } else if constexpr (EP == 1){
          v = 0.5f*v*(1.f + erff(v*0.70710678118f));
          ((ushort_t*)outp)[gm*Ncols + gn] = f2bf(v);
        } else {
          ((float*)outp)[gm*Ncols + gn] = v + resid[gm*Ncols + gn];
        }
      }
    }
  }
}

// ---------------- kv via MFMA (unchanged) ----------------
__global__ __launch_bounds__(256)
void kv_mfma_kernel(const ushort_t* __restrict__ qkv, float* __restrict__ kvT_out,
                    float* __restrict__ ksum_out){
  __shared__ __align__(16) ushort_t smem[2*48*72];   // kT [48][72], vT [48][72]
  ushort_t* kT = smem;
  ushort_t* vT = smem + 48*72;
  int bh = blockIdx.x, b = bh >> 3, h = bh & 7;
  int chunk = blockIdx.y;
  int t = threadIdx.x, lane = t & 63, wave = t >> 6;
  int lrow = lane & 15, quad = lane >> 4;
  const ushort_t* kb = qkv + (size_t)b*NN*1152 + 384 + h*48;
  const ushort_t* vb = kb + 384;
  floatx4 acc[9];
  #pragma unroll
  for (int i = 0; i < 9; ++i) acc[i] = (floatx4){0.f,0.f,0.f,0.f};
  float ks = 0.f;

  for (int s = 0; s < 7; ++s){
    int n0 = chunk*448 + s*64;
    #pragma unroll
    for (int p = 0; p < 3; ++p){
      int u = t + p*256;              // 0..767
      int arr = u / 384;              // 0=k, 1=v
      int r = u - arr*384;
      int d8 = r >> 6;                // 0..5
      int nl = r & 63;
      const ushort_t* src = (arr ? vb : kb) + (size_t)(n0 + nl)*1152 + d8*8;
      ushort_t* dst = arr ? vT : kT;
      uint4 val = *(const uint4*)src;
      ushort_t tmp[8];
      *(uint4*)tmp = val;
      #pragma unroll
      for (int j = 0; j < 8; ++j) dst[(d8*8 + j)*72 + nl] = tmp[j];
    }
    __syncthreads();
    if ((wave >> 1) == (s & 1)){
      int kloc = (wave & 1) * 32;
      short8 af[3], bfv[3];
      #pragma unroll
      for (int i = 0; i < 3; ++i) af[i]  = *(const short8*)&kT[(i*16 + lrow)*72 + kloc + quad*8];
      #pragma unroll
      for (int j = 0; j < 3; ++j) bfv[j] = *(const short8*)&vT[(j*16 + lrow)*72 + kloc + quad*8];
      #pragma unroll
      for (int i = 0; i < 3; ++i)
        #pragma unroll
        for (int j = 0; j < 3; ++j)
          acc[i*3+j] = __builtin_amdgcn_mfma_f32_16x16x32_bf16(af[i], bfv[j], acc[i*3+j], 0, 0, 0);
    }
    if (wave == 3 && lane < 48){
      float s2 = 0.f;
      #pragma unroll
      for (int q8 = 0; q8 < 8; ++q8){
        short8 kk = *(const short8*)&kT[lane*72 + q8*8];
        #pragma unroll
        for (int j = 0; j < 8; ++j) s2 += bf2f((ushort_t)kk[j]);
      }
      ks += s2;
    }
    __syncthreads();
  }

  float* F = (float*)smem;
  #define DUMP(W) if (wave == (W)){ _Pragma("unroll") for (int ti = 0; ti < 9; ++ti){ _Pragma("unroll") for (int r = 0; r < 4; ++r){ int d = (ti/3)*16 + quad*4 + r, e = (ti%3)*16 + lrow; F[d*48 + e] = acc[ti][r]; } } }
  #define ADDF(W) if (wave == (W)){ _Pragma("unroll") for (int ti = 0; ti < 9; ++ti){ _Pragma("unroll") for (int r = 0; r < 4; ++r){ int d = (ti/3)*16 + quad*4 + r, e = (ti%3)*16 + lrow; acc[ti][r] += F[d*48 + e]; } } }
  DUMP(1) __syncthreads(); ADDF(0) __syncthreads();
  DUMP(3) __syncthreads(); ADDF(2) __syncthreads();
  DUMP(2) __syncthreads(); ADDF(0) __syncthreads();
  #undef DUMP
  #undef ADDF
  if (wave == 0){
    #pragma unroll
    for (int ti = 0; ti < 9; ++ti){
      #pragma unroll
      for (int r = 0; r < 4; ++r){
        int d = (ti/3)*16 + quad*4 + r, e = (ti%3)*16 + lrow;
        atomicAdd(&kvT_out[(size_t)bh*2304 + e*48 + d], acc[ti][r]);
      }
    }
  }
  if (wave == 3 && lane < 48) atomicAdd(&ksum_out[bh*48 + lane], ks);
}

// ---------------- attn via MFMA (unchanged) ----------------
__global__ __launch_bounds__(256)
void attn_mfma_kernel(const ushort_t* __restrict__ qkv, const float* __restrict__ kvT,
                      const float* __restrict__ ksum, const float* __restrict__ temp,
                      ushort_t* __restrict__ attn_out){
  __shared__ __align__(16) ushort_t Bs[64*72];
  int bh = blockIdx.x, b = bh >> 3, h = bh & 7;
  int t = threadIdx.x, lane = t & 63, wave = t >> 6;
  int lrow = lane & 15, quad = lane >> 4;
  float tf = temp[h];
  for (int u = t; u < 64*72; u += 256){
    int col = u / 72, d = u - col*72;
    float v = 0.f;
    if (d < 48){
      if (col < 48) v = kvT[(size_t)bh*2304 + col*48 + d] * tf;
      else if (col == 48) v = ksum[bh*48 + d];
    }
    Bs[u] = f2bf(v);
  }
  __syncthreads();
  short8 bfv[4][2];
  #pragma unroll
  for (int j = 0; j < 4; ++j)
    #pragma unroll
    for (int s = 0; s < 2; ++s)
      bfv[j][s] = *(const short8*)&Bs[(j*16 + lrow)*72 + s*32 + quad*8];

  const ushort_t* qb = qkv + (size_t)b*NN*1152 + h*48;
  int n0 = blockIdx.y*256 + wave*64;
  floatx4 acc[4][4];
  #pragma unroll
  for (int i = 0; i < 4; ++i)
    #pragma unroll
    for (int j = 0; j < 4; ++j) acc[i][j] = (floatx4){0.f,0.f,0.f,0.f};

  #pragma unroll
  for (int i = 0; i < 4; ++i){
    int nrow = n0 + i*16 + lrow;
    #pragma unroll
    for (int s = 0; s < 2; ++s){
      short8 af = *(const short8*)&qb[(size_t)nrow*1152 + s*32 + quad*8];
      #pragma unroll
      for (int j = 0; j < 4; ++j)
        acc[i][j] = __builtin_amdgcn_mfma_f32_16x16x32_bf16(af, bfv[j][s], acc[i][j], 0, 0, 0);
    }
  }

  ushort_t* ob = attn_out + (size_t)b*NN*BDIM + h*48;
  #pragma unroll
  for (int i = 0; i < 4; ++i){
    #pragma unroll
    for (int r = 0; r < 4; ++r){
      float den = __shfl(acc[i][3][r], quad*16);
      den = fmaxf(den, 100.f);
      int nrow = n0 + i*16 + quad*4 + r;
      if (nrow < NN){
        #pragma unroll
        for (int j = 0; j < 3; ++j)
          ob[(size_t)nrow*BDIM + j*16 + lrow] = f2bf(acc[i][j][r] / den);
      }
    }
  }
}

extern "C" void kernel_launch(void* const* d_in, const int* in_sizes, int n_in,
                              void* d_out, int out_size, void* d_ws, size_t ws_size,
                              hipStream_t stream){
  const float* x     = (const float*)d_in[0];
  const float* cpe_w = (const float*)d_in[3];
  const float* cpe_b = (const float*)d_in[4];
  const float* ln1_w = (const float*)d_in[5];
  const float* ln1_b = (const float*)d_in[6];
  const float* qkv_w = (const float*)d_in[7];
  const float* qkv_b = (const float*)d_in[8];
  const float* temp  = (const float*)d_in[9];
  const float* proj_w= (const float*)d_in[10];
  const float* proj_b= (const float*)d_in[11];
  const float* ln2_w = (const float*)d_in[12];
  const float* ln2_b = (const float*)d_in[13];
  const float* fc1_w = (const float*)d_in[14];
  const float* fc1_b = (const float*)d_in[15];
  const float* fc2_w = (const float*)d_in[16];
  const float* fc2_b = (const float*)d_in[17];
  float* out = (float*)d_out;

  char* ws = (char*)d_ws;
  size_t off = 0;
  auto alloc = [&](size_t bytes) -> void* {
    void* p = ws + off;
    off += (bytes + 255) & ~(size_t)255;
    return p;
  };
  ushort_t* cur  = (ushort_t*)alloc((size_t)MTOT*BDIM*2);
  ushort_t* big  = (ushort_t*)alloc((size_t)MTOT*HID*2);
  float*    kvT  = (float*)   alloc((size_t)BB*HEADS*HD*HD*4);
  float*    ksum = (float*)   alloc((size_t)BB*HEADS*HD*4);
  ushort_t* wq = (ushort_t*)alloc((size_t)3*BDIM*BDIM*2);
  ushort_t* wp = (ushort_t*)alloc((size_t)BDIM*BDIM*2);
  ushort_t* w1 = (ushort_t*)alloc((size_t)HID*BDIM*2);
  ushort_t* w2 = (ushort_t*)alloc((size_t)BDIM*HID*2);

  convert_bf16_kernel<<<(3*BDIM*BDIM + 255)/256, 256, 0, stream>>>(qkv_w, wq, 3*BDIM*BDIM);
  convert_bf16_kernel<<<(BDIM*BDIM + 255)/256, 256, 0, stream>>>(proj_w, wp, BDIM*BDIM);
  convert_bf16_kernel<<<(HID*BDIM + 255)/256, 256, 0, stream>>>(fc1_w, w1, HID*BDIM);
  convert_bf16_kernel<<<(BDIM*HID + 255)/256, 256, 0, stream>>>(fc2_w, w2, BDIM*HID);

  hipMemsetAsync(kvT, 0, (size_t)BB*HEADS*HD*HD*4, stream);
  hipMemsetAsync(ksum, 0, (size_t)BB*HEADS*HD*4, stream);

  cpe_ln1_kernel<<<MTOT/(4*TPW), 256, 0, stream>>>(x, cpe_w, cpe_b, ln1_w, ln1_b, out, cur);
  gemm_kernel<0><<<dim3(9, 784), 256, 0, stream>>>(cur, wq, qkv_b, nullptr, big, 1152, BDIM);
  kv_mfma_kernel<<<dim3(BB*HEADS, 7), 256, 0, stream>>>(big, kvT, ksum);
  attn_mfma_kernel<<<dim3(BB*HEADS, 13), 256, 0, stream>>>(big, kvT, ksum, temp, cur);
  gemm_kernel<2><<<dim3(3, 784), 256, 0, stream>>>(cur, wp, proj_b, out, out, BDIM, BDIM);
  ln_kernel<<<MTOT/(4*TPW), 256, 0, stream>>>(out, ln2_w, ln2_b, cur);
  gemm_kernel<1><<<dim3(12, 784), 256, 0, stream>>>(cur, w1, fc1_b, nullptr, big, HID, BDIM);
  gemm_kernel<2><<<dim3(3, 784), 256, 0, stream>>>(big, w2, fc2_b, out, out, BDIM, HID);
}

// Round 4
// 1418.676 us; speedup vs baseline: 1.1711x; 1.0392x over previous
//
#include <hip/hip_runtime.h>
#include <hip/hip_bf16.h>
#include <math.h>

#define BDIM 384
#define HEADS 8
#define HD 48
#define HID 1536
#define BB 32
#define HH 56
#define WW 56
#define NN 3136            // 56*56
#define MTOT (BB*NN)       // 100352
#define TPW 8              // tokens per wave in cpe/ln kernels

typedef unsigned short ushort_t;
typedef __attribute__((ext_vector_type(8))) short short8;   // 8 x bf16 (4 VGPRs)
typedef __attribute__((ext_vector_type(4))) float floatx4;  // 4 x f32 acc

__device__ inline float bf2f(ushort_t u){ return __uint_as_float(((unsigned)u)<<16); }
__device__ inline ushort_t f2bf(float f){
  unsigned u = __float_as_uint(f);
  u += 0x7fff + ((u>>16)&1);   // round-to-nearest-even
  return (ushort_t)(u>>16);
}

// async global->LDS, 16B per lane; lds dest = wave-uniform base + lane*16
__device__ inline void async_ld16(const void* g, void* l){
  __builtin_amdgcn_global_load_lds((const __attribute__((address_space(1))) void*)g,
                                   (__attribute__((address_space(3))) void*)l, 16, 0, 0);
}

// ---------------- weight fp32 -> bf16 ----------------
__global__ void convert_bf16_kernel(const float* __restrict__ in, ushort_t* __restrict__ out, int n){
  int i = blockIdx.x*256 + threadIdx.x;
  if (i < n) out[i] = f2bf(in[i]);
}

// ---------------- CPE depthwise 3x3 conv + residual + LN1 (wave-per-token, no barriers) ----------------
// block 256 = 4 waves; each wave does TPW consecutive tokens; lane owns channels p*64+lane
__global__ __launch_bounds__(256)
void cpe_ln1_kernel(const float* __restrict__ x, const float* __restrict__ cw,
                    const float* __restrict__ cb, const float* __restrict__ lw,
                    const float* __restrict__ lb, float* __restrict__ x1out,
                    ushort_t* __restrict__ cur){
  int lane = threadIdx.x & 63, wave = threadIdx.x >> 6;
  size_t base = ((size_t)blockIdx.x*4 + wave) * TPW;
  float wreg[6][9], cbr[6], lwr[6], lbr[6];
  #pragma unroll
  for (int p = 0; p < 6; ++p){
    int c = p*64 + lane;
    cbr[p] = cb[c]; lwr[p] = lw[c]; lbr[p] = lb[c];
    #pragma unroll
    for (int j = 0; j < 9; ++j) wreg[p][j] = cw[c*9+j];
  }
  for (int ti = 0; ti < TPW; ++ti){
    size_t bn = base + ti;
    int b = (int)(bn / NN), n = (int)(bn % NN);
    int h = n / WW, w = n % WW;
    const float* xb = x + ((size_t)b*NN)*BDIM;
    float conv[6];
    #pragma unroll
    for (int p = 0; p < 6; ++p) conv[p] = cbr[p];
    #pragma unroll
    for (int dh = -1; dh <= 1; ++dh){
      int hh = h + dh; if ((unsigned)hh >= HH) continue;
      #pragma unroll
      for (int dw = -1; dw <= 1; ++dw){
        int w2 = w + dw; if ((unsigned)w2 >= WW) continue;
        const float* src = xb + (size_t)(hh*WW + w2)*BDIM + lane;
        int j = (dh+1)*3 + (dw+1);
        #pragma unroll
        for (int p = 0; p < 6; ++p) conv[p] += src[p*64] * wreg[p][j];
      }
    }
    const float* xc = xb + (size_t)n*BDIM + lane;
    float x1[6], s = 0.f, q = 0.f;
    #pragma unroll
    for (int p = 0; p < 6; ++p){
      x1[p] = xc[p*64] + conv[p];
      s += x1[p]; q += x1[p]*x1[p];
    }
    #pragma unroll
    for (int off = 32; off; off >>= 1){
      s += __shfl_xor(s, off);
      q += __shfl_xor(q, off);
    }
    float mean = s*(1.f/384.f);
    float rstd = rsqrtf(q*(1.f/384.f) - mean*mean + 1e-5f);
    float* xo = x1out + bn*BDIM + lane;
    ushort_t* co = cur + bn*BDIM + lane;
    #pragma unroll
    for (int p = 0; p < 6; ++p){
      xo[p*64] = x1[p];
      co[p*64] = f2bf((x1[p]-mean)*rstd*lwr[p] + lbr[p]);
    }
  }
}

// ---------------- plain LN (wave-per-token, no barriers) ----------------
__global__ __launch_bounds__(256)
void ln_kernel(const float* __restrict__ xin, const float* __restrict__ lw,
               const float* __restrict__ lb, ushort_t* __restrict__ outb){
  int lane = threadIdx.x & 63, wave = threadIdx.x >> 6;
  size_t base = ((size_t)blockIdx.x*4 + wave) * TPW;
  float lwr[6], lbr[6];
  #pragma unroll
  for (int p = 0; p < 6; ++p){ lwr[p] = lw[p*64+lane]; lbr[p] = lb[p*64+lane]; }
  for (int ti = 0; ti < TPW; ++ti){
    size_t bn = base + ti;
    const float* xi = xin + bn*BDIM + lane;
    float v[6], s = 0.f, q = 0.f;
    #pragma unroll
    for (int p = 0; p < 6; ++p){
      v[p] = xi[p*64];
      s += v[p]; q += v[p]*v[p];
    }
    #pragma unroll
    for (int off = 32; off; off >>= 1){
      s += __shfl_xor(s, off);
      q += __shfl_xor(q, off);
    }
    float mean = s*(1.f/384.f);
    float rstd = rsqrtf(q*(1.f/384.f) - mean*mean + 1e-5f);
    ushort_t* oo = outb + bn*BDIM + lane;
    #pragma unroll
    for (int p = 0; p < 6; ++p) oo[p*64] = f2bf((v[p]-mean)*rstd*lwr[p] + lbr[p]);
  }
}

// ---------------- bf16 MFMA GEMM with async global->LDS staging ----------------
// BM=BN=128, BK=64; 256 threads = 4 waves in 2x2; each wave: 4x4 tiles of 16x16,
// 2 k-halves per K-step (32 MFMA/step). BK=64 halves the number of per-iteration
// vmcnt(0)+barrier drains (the measured bottleneck: MfmaUtil 17%, HBM 18%, both idle;
// per-block-iter cost 1562 cyc vs m97's 736 -> drain-dominated). LDS stores the BK=64
// tile as TWO contiguous [128][32] sub-tiles (lo-k / hi-k) so the ds_read bank-conflict
// pattern stays at the current measured-tolerable level (a flat [128][64] would be a
// 16-way conflict, G4), and global_load_lds's linear-dest constraint is preserved.
// Accumulation order is identical to two consecutive BK=32 steps (bit-identical result).
template<int EP>
__global__ __launch_bounds__(256)
void gemm_kernel(const ushort_t* __restrict__ A, const ushort_t* __restrict__ Bw,
                 const float* __restrict__ bias, const float* __restrict__ resid,
                 void* __restrict__ outp, int Ncols, int K){
  __shared__ __align__(16) ushort_t As[2*128*32];   // [half][row][32]
  __shared__ __align__(16) ushort_t Bs[2*128*32];
  const int t = threadIdx.x;
  const int lane = t & 63, wave = t >> 6;
  const int wm = wave >> 1, wn = wave & 1;

  // bijective XCD-aware remap (m204). All our grids have nwg % 8 == 0.
  // Keeps FETCH_SIZE low (550->253 MB measured on fc2).
  const int gx = gridDim.x;
  const int nwg = gx * gridDim.y;
  int orig = blockIdx.y * gx + blockIdx.x;
  int qn = nwg >> 3, rn = nwg & 7;
  int xcd = orig & 7, pos = orig >> 3;
  int wg = (xcd < rn ? xcd*(qn+1) : rn*(qn+1) + (xcd-rn)*qn) + pos;
  int bx = wg % gx;
  int by = wg / gx;

  const size_t m0 = (size_t)by * 128;
  const int n0 = bx * 128;
  const int lrow = lane & 15, lk = (lane >> 4) << 3;
  floatx4 zero4 = {0.f, 0.f, 0.f, 0.f};
  floatx4 acc[4][4];
  #pragma unroll
  for (int i = 0; i < 4; ++i)
    #pragma unroll
    for (int j = 0; j < 4; ++j) acc[i][j] = zero4;

  for (int k0 = 0; k0 < K; k0 += 64){
    // stage BK=64 tile pair: idx 0..1023 -> half=idx>>9 (k 0-31 / 32-63),
    // row=(idx>>2)&127, chunk=idx&3; LDS offset = idx*8 (linear, matches lane order)
    #pragma unroll
    for (int l = 0; l < 4; ++l){
      int idx = t + l*256;                       // 0..1023
      int row = (idx >> 2) & 127;
      int ko  = (idx >> 9)*32 + (idx & 3)*8;     // 0..56
      int lbase = (l*256 + wave*64) * 8;         // wave-uniform LDS elem base
      async_ld16(&A[(m0 + row)*K + (k0 + ko)], &As[lbase]);
      async_ld16(&Bw[(size_t)(n0 + row)*K + (k0 + ko)], &Bs[lbase]);
    }
    __syncthreads();
    #pragma unroll
    for (int half = 0; half < 2; ++half){
      const ushort_t* Ah = &As[half*4096];
      const ushort_t* Bh = &Bs[half*4096];
      short8 af[4], bfr[4];
      #pragma unroll
      for (int i = 0; i < 4; ++i) af[i]  = *(const short8*)&Ah[(wm*64 + i*16 + lrow)*32 + lk];
      #pragma unroll
      for (int j = 0; j < 4; ++j) bfr[j] = *(const short8*)&Bh[(wn*64 + j*16 + lrow)*32 + lk];
      #pragma unroll
      for (int i = 0; i < 4; ++i)
        #pragma unroll
        for (int j = 0; j < 4; ++j)
          acc[i][j] = __builtin_amdgcn_mfma_f32_16x16x32_bf16(af[i], bfr[j], acc[i][j], 0, 0, 0);
    }
    __syncthreads();
  }

  const int quad = lane >> 4;
  #pragma unroll
  for (int i = 0; i < 4; ++i){
    #pragma unroll
    for (int j = 0; j < 4; ++j){
      int gn = n0 + wn*64 + j*16 + lrow;
      float bv = bias[gn];
      #pragma unroll
      for (int r = 0; r < 4; ++r){
        size_t gm = m0 + wm*64 + i*16 + quad*4 + r;
        float v = acc[i][j][r] + bv;
        if constexpr (EP == 0){
          if (gn < 768) v = fmaxf(v, 0.f);
          ((ushort_t*)outp)[gm*Ncols + gn] = f2bf(v);
        } else if constexpr (EP == 1){
          v = 0.5f*v*(1.f + erff(v*0.70710678118f));
          ((ushort_t*)outp)[gm*Ncols + gn] = f2bf(v);
        } else {
          ((float*)outp)[gm*Ncols + gn] = v + resid[gm*Ncols + gn];
        }
      }
    }
  }
}

// ---------------- kv via MFMA (unchanged) ----------------
__global__ __launch_bounds__(256)
void kv_mfma_kernel(const ushort_t* __restrict__ qkv, float* __restrict__ kvT_out,
                    float* __restrict__ ksum_out){
  __shared__ __align__(16) ushort_t smem[2*48*72];   // kT [48][72], vT [48][72]
  ushort_t* kT = smem;
  ushort_t* vT = smem + 48*72;
  int bh = blockIdx.x, b = bh >> 3, h = bh & 7;
  int chunk = blockIdx.y;
  int t = threadIdx.x, lane = t & 63, wave = t >> 6;
  int lrow = lane & 15, quad = lane >> 4;
  const ushort_t* kb = qkv + (size_t)b*NN*1152 + 384 + h*48;
  const ushort_t* vb = kb + 384;
  floatx4 acc[9];
  #pragma unroll
  for (int i = 0; i < 9; ++i) acc[i] = (floatx4){0.f,0.f,0.f,0.f};
  float ks = 0.f;

  for (int s = 0; s < 7; ++s){
    int n0 = chunk*448 + s*64;
    #pragma unroll
    for (int p = 0; p < 3; ++p){
      int u = t + p*256;              // 0..767
      int arr = u / 384;              // 0=k, 1=v
      int r = u - arr*384;
      int d8 = r >> 6;                // 0..5
      int nl = r & 63;
      const ushort_t* src = (arr ? vb : kb) + (size_t)(n0 + nl)*1152 + d8*8;
      ushort_t* dst = arr ? vT : kT;
      uint4 val = *(const uint4*)src;
      ushort_t tmp[8];
      *(uint4*)tmp = val;
      #pragma unroll
      for (int j = 0; j < 8; ++j) dst[(d8*8 + j)*72 + nl] = tmp[j];
    }
    __syncthreads();
    if ((wave >> 1) == (s & 1)){
      int kloc = (wave & 1) * 32;
      short8 af[3], bfv[3];
      #pragma unroll
      for (int i = 0; i < 3; ++i) af[i]  = *(const short8*)&kT[(i*16 + lrow)*72 + kloc + quad*8];
      #pragma unroll
      for (int j = 0; j < 3; ++j) bfv[j] = *(const short8*)&vT[(j*16 + lrow)*72 + kloc + quad*8];
      #pragma unroll
      for (int i = 0; i < 3; ++i)
        #pragma unroll
        for (int j = 0; j < 3; ++j)
          acc[i*3+j] = __builtin_amdgcn_mfma_f32_16x16x32_bf16(af[i], bfv[j], acc[i*3+j], 0, 0, 0);
    }
    if (wave == 3 && lane < 48){
      float s2 = 0.f;
      #pragma unroll
      for (int q8 = 0; q8 < 8; ++q8){
        short8 kk = *(const short8*)&kT[lane*72 + q8*8];
        #pragma unroll
        for (int j = 0; j < 8; ++j) s2 += bf2f((ushort_t)kk[j]);
      }
      ks += s2;
    }
    __syncthreads();
  }

  float* F = (float*)smem;
  #define DUMP(W) if (wave == (W)){ _Pragma("unroll") for (int ti = 0; ti < 9; ++ti){ _Pragma("unroll") for (int r = 0; r < 4; ++r){ int d = (ti/3)*16 + quad*4 + r, e = (ti%3)*16 + lrow; F[d*48 + e] = acc[ti][r]; } } }
  #define ADDF(W) if (wave == (W)){ _Pragma("unroll") for (int ti = 0; ti < 9; ++ti){ _Pragma("unroll") for (int r = 0; r < 4; ++r){ int d = (ti/3)*16 + quad*4 + r, e = (ti%3)*16 + lrow; acc[ti][r] += F[d*48 + e]; } } }
  DUMP(1) __syncthreads(); ADDF(0) __syncthreads();
  DUMP(3) __syncthreads(); ADDF(2) __syncthreads();
  DUMP(2) __syncthreads(); ADDF(0) __syncthreads();
  #undef DUMP
  #undef ADDF
  if (wave == 0){
    #pragma unroll
    for (int ti = 0; ti < 9; ++ti){
      #pragma unroll
      for (int r = 0; r < 4; ++r){
        int d = (ti/3)*16 + quad*4 + r, e = (ti%3)*16 + lrow;
        atomicAdd(&kvT_out[(size_t)bh*2304 + e*48 + d], acc[ti][r]);
      }
    }
  }
  if (wave == 3 && lane < 48) atomicAdd(&ksum_out[bh*48 + lane], ks);
}

// ---------------- attn via MFMA (unchanged) ----------------
__global__ __launch_bounds__(256)
void attn_mfma_kernel(const ushort_t* __restrict__ qkv, const float* __restrict__ kvT,
                      const float* __restrict__ ksum, const float* __restrict__ temp,
                      ushort_t* __restrict__ attn_out){
  __shared__ __align__(16) ushort_t Bs[64*72];
  int bh = blockIdx.x, b = bh >> 3, h = bh & 7;
  int t = threadIdx.x, lane = t & 63, wave = t >> 6;
  int lrow = lane & 15, quad = lane >> 4;
  float tf = temp[h];
  for (int u = t; u < 64*72; u += 256){
    int col = u / 72, d = u - col*72;
    float v = 0.f;
    if (d < 48){
      if (col < 48) v = kvT[(size_t)bh*2304 + col*48 + d] * tf;
      else if (col == 48) v = ksum[bh*48 + d];
    }
    Bs[u] = f2bf(v);
  }
  __syncthreads();
  short8 bfv[4][2];
  #pragma unroll
  for (int j = 0; j < 4; ++j)
    #pragma unroll
    for (int s = 0; s < 2; ++s)
      bfv[j][s] = *(const short8*)&Bs[(j*16 + lrow)*72 + s*32 + quad*8];

  const ushort_t* qb = qkv + (size_t)b*NN*1152 + h*48;
  int n0 = blockIdx.y*256 + wave*64;
  floatx4 acc[4][4];
  #pragma unroll
  for (int i = 0; i < 4; ++i)
    #pragma unroll
    for (int j = 0; j < 4; ++j) acc[i][j] = (floatx4){0.f,0.f,0.f,0.f};

  #pragma unroll
  for (int i = 0; i < 4; ++i){
    int nrow = n0 + i*16 + lrow;
    #pragma unroll
    for (int s = 0; s < 2; ++s){
      short8 af = *(const short8*)&qb[(size_t)nrow*1152 + s*32 + quad*8];
      #pragma unroll
      for (int j = 0; j < 4; ++j)
        acc[i][j] = __builtin_amdgcn_mfma_f32_16x16x32_bf16(af, bfv[j][s], acc[i][j], 0, 0, 0);
    }
  }

  ushort_t* ob = attn_out + (size_t)b*NN*BDIM + h*48;
  #pragma unroll
  for (int i = 0; i < 4; ++i){
    #pragma unroll
    for (int r = 0; r < 4; ++r){
      float den = __shfl(acc[i][3][r], quad*16);
      den = fmaxf(den, 100.f);
      int nrow = n0 + i*16 + quad*4 + r;
      if (nrow < NN){
        #pragma unroll
        for (int j = 0; j < 3; ++j)
          ob[(size_t)nrow*BDIM + j*16 + lrow] = f2bf(acc[i][j][r] / den);
      }
    }
  }
}

extern "C" void kernel_launch(void* const* d_in, const int* in_sizes, int n_in,
                              void* d_out, int out_size, void* d_ws, size_t ws_size,
                              hipStream_t stream){
  const float* x     = (const float*)d_in[0];
  const float* cpe_w = (const float*)d_in[3];
  const float* cpe_b = (const float*)d_in[4];
  const float* ln1_w = (const float*)d_in[5];
  const float* ln1_b = (const float*)d_in[6];
  const float* qkv_w = (const float*)d_in[7];
  const float* qkv_b = (const float*)d_in[8];
  const float* temp  = (const float*)d_in[9];
  const float* proj_w= (const float*)d_in[10];
  const float* proj_b= (const float*)d_in[11];
  const float* ln2_w = (const float*)d_in[12];
  const float* ln2_b = (const float*)d_in[13];
  const float* fc1_w = (const float*)d_in[14];
  const float* fc1_b = (const float*)d_in[15];
  const float* fc2_w = (const float*)d_in[16];
  const float* fc2_b = (const float*)d_in[17];
  float* out = (float*)d_out;

  char* ws = (char*)d_ws;
  size_t off = 0;
  auto alloc = [&](size_t bytes) -> void* {
    void* p = ws + off;
    off += (bytes + 255) & ~(size_t)255;
    return p;
  };
  ushort_t* cur  = (ushort_t*)alloc((size_t)MTOT*BDIM*2);
  ushort_t* big  = (ushort_t*)alloc((size_t)MTOT*HID*2);
  float*    kvT  = (float*)   alloc((size_t)BB*HEADS*HD*HD*4);
  float*    ksum = (float*)   alloc((size_t)BB*HEADS*HD*4);
  ushort_t* wq = (ushort_t*)alloc((size_t)3*BDIM*BDIM*2);
  ushort_t* wp = (ushort_t*)alloc((size_t)BDIM*BDIM*2);
  ushort_t* w1 = (ushort_t*)alloc((size_t)HID*BDIM*2);
  ushort_t* w2 = (ushort_t*)alloc((size_t)BDIM*HID*2);

  convert_bf16_kernel<<<(3*BDIM*BDIM + 255)/256, 256, 0, stream>>>(qkv_w, wq, 3*BDIM*BDIM);
  convert_bf16_kernel<<<(BDIM*BDIM + 255)/256, 256, 0, stream>>>(proj_w, wp, BDIM*BDIM);
  convert_bf16_kernel<<<(HID*BDIM + 255)/256, 256, 0, stream>>>(fc1_w, w1, HID*BDIM);
  convert_bf16_kernel<<<(BDIM*HID + 255)/256, 256, 0, stream>>>(fc2_w, w2, BDIM*HID);

  hipMemsetAsync(kvT, 0, (size_t)BB*HEADS*HD*HD*4, stream);
  hipMemsetAsync(ksum, 0, (size_t)BB*HEADS*HD*4, stream);

  cpe_ln1_kernel<<<MTOT/(4*TPW), 256, 0, stream>>>(x, cpe_w, cpe_b, ln1_w, ln1_b, out, cur);
  gemm_kernel<0><<<dim3(9, 784), 256, 0, stream>>>(cur, wq, qkv_b, nullptr, big, 1152, BDIM);
  kv_mfma_kernel<<<dim3(BB*HEADS, 7), 256, 0, stream>>>(big, kvT, ksum);
  attn_mfma_kernel<<<dim3(BB*HEADS, 13), 256, 0, stream>>>(big, kvT, ksum, temp, cur);
  gemm_kernel<2><<<dim3(3, 784), 256, 0, stream>>>(cur, wp, proj_b, out, out, BDIM, BDIM);
  ln_kernel<<<MTOT/(4*TPW), 256, 0, stream>>>(out, ln2_w, ln2_b, cur);
  gemm_kernel<1><<<dim3(12, 784), 256, 0, stream>>>(cur, w1, fc1_b, nullptr, big, HID, BDIM);
  gemm_kernel<2><<<dim3(3, 784), 256, 0, stream>>>(big, w2, fc2_b, out, out, BDIM, HID);
}

// Round 5
// 1398.999 us; speedup vs baseline: 1.1876x; 1.0141x over previous
//
#include <hip/hip_runtime.h>
#include <hip/hip_bf16.h>
#include <math.h>

#define BDIM 384
#define HEADS 8
#define HD 48
#define HID 1536
#define BB 32
#define HH 56
#define WW 56
#define NN 3136            // 56*56
#define MTOT (BB*NN)       // 100352
#define TPW 8              // tokens per wave in cpe/ln kernels

typedef unsigned short ushort_t;
typedef __attribute__((ext_vector_type(8))) short short8;   // 8 x bf16 (4 VGPRs)
typedef __attribute__((ext_vector_type(4))) float floatx4;  // 4 x f32 acc

__device__ inline float bf2f(ushort_t u){ return __uint_as_float(((unsigned)u)<<16); }
__device__ inline ushort_t f2bf(float f){
  unsigned u = __float_as_uint(f);
  u += 0x7fff + ((u>>16)&1);   // round-to-nearest-even
  return (ushort_t)(u>>16);
}

// fast erf (Abramowitz-Stegun 7.1.26, max abs err 1.5e-7 << bf16 ulp)
__device__ inline float erf_fast(float z){
  float az = fabsf(z);
  float tt = 1.f/(1.f + 0.3275911f*az);
  float poly = tt*(0.254829592f + tt*(-0.284496736f + tt*(1.421413741f +
               tt*(-1.453152027f + tt*1.061405429f))));
  float e = exp2f(-az*az*1.4426950408889634f);
  float r = 1.f - poly*e;
  return copysignf(r, z);
}

// async global->LDS, 16B per lane; lds dest = wave-uniform base + lane*16
__device__ inline void async_ld16(const void* g, void* l){
  __builtin_amdgcn_global_load_lds((const __attribute__((address_space(1))) void*)g,
                                   (__attribute__((address_space(3))) void*)l, 16, 0, 0);
}

// ---------------- weight fp32 -> bf16 ----------------
__global__ void convert_bf16_kernel(const float* __restrict__ in, ushort_t* __restrict__ out, int n){
  int i = blockIdx.x*256 + threadIdx.x;
  if (i < n) out[i] = f2bf(in[i]);
}

// ---------------- CPE depthwise 3x3 conv + residual + LN1 (wave-per-token, no barriers) ----------------
__global__ __launch_bounds__(256)
void cpe_ln1_kernel(const float* __restrict__ x, const float* __restrict__ cw,
                    const float* __restrict__ cb, const float* __restrict__ lw,
                    const float* __restrict__ lb, float* __restrict__ x1out,
                    ushort_t* __restrict__ cur){
  int lane = threadIdx.x & 63, wave = threadIdx.x >> 6;
  size_t base = ((size_t)blockIdx.x*4 + wave) * TPW;
  float wreg[6][9], cbr[6], lwr[6], lbr[6];
  #pragma unroll
  for (int p = 0; p < 6; ++p){
    int c = p*64 + lane;
    cbr[p] = cb[c]; lwr[p] = lw[c]; lbr[p] = lb[c];
    #pragma unroll
    for (int j = 0; j < 9; ++j) wreg[p][j] = cw[c*9+j];
  }
  for (int ti = 0; ti < TPW; ++ti){
    size_t bn = base + ti;
    int b = (int)(bn / NN), n = (int)(bn % NN);
    int h = n / WW, w = n % WW;
    const float* xb = x + ((size_t)b*NN)*BDIM;
    float conv[6];
    #pragma unroll
    for (int p = 0; p < 6; ++p) conv[p] = cbr[p];
    #pragma unroll
    for (int dh = -1; dh <= 1; ++dh){
      int hh = h + dh; if ((unsigned)hh >= HH) continue;
      #pragma unroll
      for (int dw = -1; dw <= 1; ++dw){
        int w2 = w + dw; if ((unsigned)w2 >= WW) continue;
        const float* src = xb + (size_t)(hh*WW + w2)*BDIM + lane;
        int j = (dh+1)*3 + (dw+1);
        #pragma unroll
        for (int p = 0; p < 6; ++p) conv[p] += src[p*64] * wreg[p][j];
      }
    }
    const float* xc = xb + (size_t)n*BDIM + lane;
    float x1[6], s = 0.f, q = 0.f;
    #pragma unroll
    for (int p = 0; p < 6; ++p){
      x1[p] = xc[p*64] + conv[p];
      s += x1[p]; q += x1[p]*x1[p];
    }
    #pragma unroll
    for (int off = 32; off; off >>= 1){
      s += __shfl_xor(s, off);
      q += __shfl_xor(q, off);
    }
    float mean = s*(1.f/384.f);
    float rstd = rsqrtf(q*(1.f/384.f) - mean*mean + 1e-5f);
    float* xo = x1out + bn*BDIM + lane;
    ushort_t* co = cur + bn*BDIM + lane;
    #pragma unroll
    for (int p = 0; p < 6; ++p){
      xo[p*64] = x1[p];
      co[p*64] = f2bf((x1[p]-mean)*rstd*lwr[p] + lbr[p]);
    }
  }
}

// ---------------- plain LN (wave-per-token, no barriers) ----------------
__global__ __launch_bounds__(256)
void ln_kernel(const float* __restrict__ xin, const float* __restrict__ lw,
               const float* __restrict__ lb, ushort_t* __restrict__ outb){
  int lane = threadIdx.x & 63, wave = threadIdx.x >> 6;
  size_t base = ((size_t)blockIdx.x*4 + wave) * TPW;
  float lwr[6], lbr[6];
  #pragma unroll
  for (int p = 0; p < 6; ++p){ lwr[p] = lw[p*64+lane]; lbr[p] = lb[p*64+lane]; }
  for (int ti = 0; ti < TPW; ++ti){
    size_t bn = base + ti;
    const float* xi = xin + bn*BDIM + lane;
    float v[6], s = 0.f, q = 0.f;
    #pragma unroll
    for (int p = 0; p < 6; ++p){
      v[p] = xi[p*64];
      s += v[p]; q += v[p]*v[p];
    }
    #pragma unroll
    for (int off = 32; off; off >>= 1){
      s += __shfl_xor(s, off);
      q += __shfl_xor(q, off);
    }
    float mean = s*(1.f/384.f);
    float rstd = rsqrtf(q*(1.f/384.f) - mean*mean + 1e-5f);
    ushort_t* oo = outb + bn*BDIM + lane;
    #pragma unroll
    for (int p = 0; p < 6; ++p) oo[p*64] = f2bf((v[p]-mean)*rstd*lwr[p] + lbr[p]);
  }
}

// ---------------- bf16 MFMA GEMM with async global->LDS staging ----------------
// BM=256, BN=128, BK=64; 512 threads = 8 waves in 4M x 2N; each wave: 4x4 tiles
// of 16x16 over its 64x64 sub-tile, 2 k-halves per K-step (32 MFMA/wave/step).
// Rationale (round-4 counters): MfmaUtil 19% with ~900-cyc drain per K-step buying
// only 32 MFMA/wave. BM=256 doubles MFMA work per drain (256 MFMA/block-step vs
// 12 gload_lds) so resident blocks can cover the drain latency. LDS stores BK=64
// as two [*][32] sub-tiles (lo/hi k) keeping the measured-tolerable conflict level;
// the global source index is pre-permuted so the LINEAR gload_lds dest (idx*8)
// lands exactly at [half][row][32]. Accumulation order identical to BK=32 steps.
template<int EP>
__global__ __launch_bounds__(512)
void gemm_kernel(const ushort_t* __restrict__ A, const ushort_t* __restrict__ Bw,
                 const float* __restrict__ bias, const float* __restrict__ resid,
                 void* __restrict__ outp, int Ncols, int K){
  __shared__ __align__(16) ushort_t As[2*256*32];   // 32 KB: [half][row 0..255][32]
  __shared__ __align__(16) ushort_t Bs[2*128*32];   // 16 KB: [half][row 0..127][32]
  const int t = threadIdx.x;
  const int lane = t & 63, wave = t >> 6;           // 8 waves
  const int wm = wave >> 1, wn = wave & 1;          // 4M x 2N

  // bijective XCD-aware remap (m204). All our grids have nwg % 8 == 0.
  const int gx = gridDim.x;
  const int nwg = gx * gridDim.y;
  int orig = blockIdx.y * gx + blockIdx.x;
  int qn = nwg >> 3, rn = nwg & 7;
  int xcd = orig & 7, pos = orig >> 3;
  int wg = (xcd < rn ? xcd*(qn+1) : rn*(qn+1) + (xcd-rn)*qn) + pos;
  int bx = wg % gx;
  int by = wg / gx;

  const size_t m0 = (size_t)by * 256;
  const int n0 = bx * 128;
  const int lrow = lane & 15, lk = (lane >> 4) << 3;
  floatx4 zero4 = {0.f, 0.f, 0.f, 0.f};
  floatx4 acc[4][4];
  #pragma unroll
  for (int i = 0; i < 4; ++i)
    #pragma unroll
    for (int j = 0; j < 4; ++j) acc[i][j] = zero4;

  for (int k0 = 0; k0 < K; k0 += 64){
    // A: 2048 lane-loads (4 rounds); dest elem off = idx*8 == half*8192+row*32+ksub
    //    with idx = half*1024 + row*4 + ksub/8  ->  row=(idx>>2)&255, half=idx>>10
    // B: 1024 lane-loads (2 rounds); idx = half*512 + row*4 + ksub/8
    #pragma unroll
    for (int l = 0; l < 4; ++l){
      int idx = t + l*512;
      int lbase = (l*512 + wave*64) * 8;           // wave-uniform LDS elem base
      int arow = (idx >> 2) & 255;
      int ako  = (idx >> 10)*32 + (idx & 3)*8;
      async_ld16(&A[(m0 + arow)*K + (k0 + ako)], &As[lbase]);
      if (l < 2){
        int brow = (idx >> 2) & 127;
        int bko  = (idx >> 9)*32 + (idx & 3)*8;
        async_ld16(&Bw[(size_t)(n0 + brow)*K + (k0 + bko)], &Bs[lbase]);
      }
    }
    __syncthreads();
    #pragma unroll
    for (int half = 0; half < 2; ++half){
      const ushort_t* Ah = &As[half*8192];
      const ushort_t* Bh = &Bs[half*4096];
      short8 af[4], bfr[4];
      #pragma unroll
      for (int i = 0; i < 4; ++i) af[i]  = *(const short8*)&Ah[(wm*64 + i*16 + lrow)*32 + lk];
      #pragma unroll
      for (int j = 0; j < 4; ++j) bfr[j] = *(const short8*)&Bh[(wn*64 + j*16 + lrow)*32 + lk];
      #pragma unroll
      for (int i = 0; i < 4; ++i)
        #pragma unroll
        for (int j = 0; j < 4; ++j)
          acc[i][j] = __builtin_amdgcn_mfma_f32_16x16x32_bf16(af[i], bfr[j], acc[i][j], 0, 0, 0);
    }
    __syncthreads();
  }

  const int quad = lane >> 4;
  #pragma unroll
  for (int i = 0; i < 4; ++i){
    #pragma unroll
    for (int j = 0; j < 4; ++j){
      int gn = n0 + wn*64 + j*16 + lrow;
      float bv = bias[gn];
      #pragma unroll
      for (int r = 0; r < 4; ++r){
        size_t gm = m0 + wm*64 + i*16 + quad*4 + r;
        float v = acc[i][j][r] + bv;
        if constexpr (EP == 0){
          if (gn < 768) v = fmaxf(v, 0.f);
          ((ushort_t*)outp)[gm*Ncols + gn] = f2bf(v);
        } else if constexpr (EP == 1){
          v = 0.5f*v*(1.f + erf_fast(v*0.70710678118f));
          ((ushort_t*)outp)[gm*Ncols + gn] = f2bf(v);
        } else {
          ((float*)outp)[gm*Ncols + gn] = v + resid[gm*Ncols + gn];
        }
      }
    }
  }
}

// ---------------- kv via MFMA (unchanged) ----------------
__global__ __launch_bounds__(256)
void kv_mfma_kernel(const ushort_t* __restrict__ qkv, float* __restrict__ kvT_out,
                    float* __restrict__ ksum_out){
  __shared__ __align__(16) ushort_t smem[2*48*72];   // kT [48][72], vT [48][72]
  ushort_t* kT = smem;
  ushort_t* vT = smem + 48*72;
  int bh = blockIdx.x, b = bh >> 3, h = bh & 7;
  int chunk = blockIdx.y;
  int t = threadIdx.x, lane = t & 63, wave = t >> 6;
  int lrow = lane & 15, quad = lane >> 4;
  const ushort_t* kb = qkv + (size_t)b*NN*1152 + 384 + h*48;
  const ushort_t* vb = kb + 384;
  floatx4 acc[9];
  #pragma unroll
  for (int i = 0; i < 9; ++i) acc[i] = (floatx4){0.f,0.f,0.f,0.f};
  float ks = 0.f;

  for (int s = 0; s < 7; ++s){
    int n0 = chunk*448 + s*64;
    #pragma unroll
    for (int p = 0; p < 3; ++p){
      int u = t + p*256;              // 0..767
      int arr = u / 384;              // 0=k, 1=v
      int r = u - arr*384;
      int d8 = r >> 6;                // 0..5
      int nl = r & 63;
      const ushort_t* src = (arr ? vb : kb) + (size_t)(n0 + nl)*1152 + d8*8;
      ushort_t* dst = arr ? vT : kT;
      uint4 val = *(const uint4*)src;
      ushort_t tmp[8];
      *(uint4*)tmp = val;
      #pragma unroll
      for (int j = 0; j < 8; ++j) dst[(d8*8 + j)*72 + nl] = tmp[j];
    }
    __syncthreads();
    if ((wave >> 1) == (s & 1)){
      int kloc = (wave & 1) * 32;
      short8 af[3], bfv[3];
      #pragma unroll
      for (int i = 0; i < 3; ++i) af[i]  = *(const short8*)&kT[(i*16 + lrow)*72 + kloc + quad*8];
      #pragma unroll
      for (int j = 0; j < 3; ++j) bfv[j] = *(const short8*)&vT[(j*16 + lrow)*72 + kloc + quad*8];
      #pragma unroll
      for (int i = 0; i < 3; ++i)
        #pragma unroll
        for (int j = 0; j < 3; ++j)
          acc[i*3+j] = __builtin_amdgcn_mfma_f32_16x16x32_bf16(af[i], bfv[j], acc[i*3+j], 0, 0, 0);
    }
    if (wave == 3 && lane < 48){
      float s2 = 0.f;
      #pragma unroll
      for (int q8 = 0; q8 < 8; ++q8){
        short8 kk = *(const short8*)&kT[lane*72 + q8*8];
        #pragma unroll
        for (int j = 0; j < 8; ++j) s2 += bf2f((ushort_t)kk[j]);
      }
      ks += s2;
    }
    __syncthreads();
  }

  float* F = (float*)smem;
  #define DUMP(W) if (wave == (W)){ _Pragma("unroll") for (int ti = 0; ti < 9; ++ti){ _Pragma("unroll") for (int r = 0; r < 4; ++r){ int d = (ti/3)*16 + quad*4 + r, e = (ti%3)*16 + lrow; F[d*48 + e] = acc[ti][r]; } } }
  #define ADDF(W) if (wave == (W)){ _Pragma("unroll") for (int ti = 0; ti < 9; ++ti){ _Pragma("unroll") for (int r = 0; r < 4; ++r){ int d = (ti/3)*16 + quad*4 + r, e = (ti%3)*16 + lrow; acc[ti][r] += F[d*48 + e]; } } }
  DUMP(1) __syncthreads(); ADDF(0) __syncthreads();
  DUMP(3) __syncthreads(); ADDF(2) __syncthreads();
  DUMP(2) __syncthreads(); ADDF(0) __syncthreads();
  #undef DUMP
  #undef ADDF
  if (wave == 0){
    #pragma unroll
    for (int ti = 0; ti < 9; ++ti){
      #pragma unroll
      for (int r = 0; r < 4; ++r){
        int d = (ti/3)*16 + quad*4 + r, e = (ti%3)*16 + lrow;
        atomicAdd(&kvT_out[(size_t)bh*2304 + e*48 + d], acc[ti][r]);
      }
    }
  }
  if (wave == 3 && lane < 48) atomicAdd(&ksum_out[bh*48 + lane], ks);
}

// ---------------- attn via MFMA (unchanged) ----------------
__global__ __launch_bounds__(256)
void attn_mfma_kernel(const ushort_t* __restrict__ qkv, const float* __restrict__ kvT,
                      const float* __restrict__ ksum, const float* __restrict__ temp,
                      ushort_t* __restrict__ attn_out){
  __shared__ __align__(16) ushort_t Bs[64*72];
  int bh = blockIdx.x, b = bh >> 3, h = bh & 7;
  int t = threadIdx.x, lane = t & 63, wave = t >> 6;
  int lrow = lane & 15, quad = lane >> 4;
  float tf = temp[h];
  for (int u = t; u < 64*72; u += 256){
    int col = u / 72, d = u - col*72;
    float v = 0.f;
    if (d < 48){
      if (col < 48) v = kvT[(size_t)bh*2304 + col*48 + d] * tf;
      else if (col == 48) v = ksum[bh*48 + d];
    }
    Bs[u] = f2bf(v);
  }
  __syncthreads();
  short8 bfv[4][2];
  #pragma unroll
  for (int j = 0; j < 4; ++j)
    #pragma unroll
    for (int s = 0; s < 2; ++s)
      bfv[j][s] = *(const short8*)&Bs[(j*16 + lrow)*72 + s*32 + quad*8];

  const ushort_t* qb = qkv + (size_t)b*NN*1152 + h*48;
  int n0 = blockIdx.y*256 + wave*64;
  floatx4 acc[4][4];
  #pragma unroll
  for (int i = 0; i < 4; ++i)
    #pragma unroll
    for (int j = 0; j < 4; ++j) acc[i][j] = (floatx4){0.f,0.f,0.f,0.f};

  #pragma unroll
  for (int i = 0; i < 4; ++i){
    int nrow = n0 + i*16 + lrow;
    #pragma unroll
    for (int s = 0; s < 2; ++s){
      short8 af = *(const short8*)&qb[(size_t)nrow*1152 + s*32 + quad*8];
      #pragma unroll
      for (int j = 0; j < 4; ++j)
        acc[i][j] = __builtin_amdgcn_mfma_f32_16x16x32_bf16(af, bfv[j][s], acc[i][j], 0, 0, 0);
    }
  }

  ushort_t* ob = attn_out + (size_t)b*NN*BDIM + h*48;
  #pragma unroll
  for (int i = 0; i < 4; ++i){
    #pragma unroll
    for (int r = 0; r < 4; ++r){
      float den = __shfl(acc[i][3][r], quad*16);
      den = fmaxf(den, 100.f);
      int nrow = n0 + i*16 + quad*4 + r;
      if (nrow < NN){
        #pragma unroll
        for (int j = 0; j < 3; ++j)
          ob[(size_t)nrow*BDIM + j*16 + lrow] = f2bf(acc[i][j][r] / den);
      }
    }
  }
}

extern "C" void kernel_launch(void* const* d_in, const int* in_sizes, int n_in,
                              void* d_out, int out_size, void* d_ws, size_t ws_size,
                              hipStream_t stream){
  const float* x     = (const float*)d_in[0];
  const float* cpe_w = (const float*)d_in[3];
  const float* cpe_b = (const float*)d_in[4];
  const float* ln1_w = (const float*)d_in[5];
  const float* ln1_b = (const float*)d_in[6];
  const float* qkv_w = (const float*)d_in[7];
  const float* qkv_b = (const float*)d_in[8];
  const float* temp  = (const float*)d_in[9];
  const float* proj_w= (const float*)d_in[10];
  const float* proj_b= (const float*)d_in[11];
  const float* ln2_w = (const float*)d_in[12];
  const float* ln2_b = (const float*)d_in[13];
  const float* fc1_w = (const float*)d_in[14];
  const float* fc1_b = (const float*)d_in[15];
  const float* fc2_w = (const float*)d_in[16];
  const float* fc2_b = (const float*)d_in[17];
  float* out = (float*)d_out;

  char* ws = (char*)d_ws;
  size_t off = 0;
  auto alloc = [&](size_t bytes) -> void* {
    void* p = ws + off;
    off += (bytes + 255) & ~(size_t)255;
    return p;
  };
  ushort_t* cur  = (ushort_t*)alloc((size_t)MTOT*BDIM*2);
  ushort_t* big  = (ushort_t*)alloc((size_t)MTOT*HID*2);
  float*    kvT  = (float*)   alloc((size_t)BB*HEADS*HD*HD*4);
  float*    ksum = (float*)   alloc((size_t)BB*HEADS*HD*4);
  ushort_t* wq = (ushort_t*)alloc((size_t)3*BDIM*BDIM*2);
  ushort_t* wp = (ushort_t*)alloc((size_t)BDIM*BDIM*2);
  ushort_t* w1 = (ushort_t*)alloc((size_t)HID*BDIM*2);
  ushort_t* w2 = (ushort_t*)alloc((size_t)BDIM*HID*2);

  convert_bf16_kernel<<<(3*BDIM*BDIM + 255)/256, 256, 0, stream>>>(qkv_w, wq, 3*BDIM*BDIM);
  convert_bf16_kernel<<<(BDIM*BDIM + 255)/256, 256, 0, stream>>>(proj_w, wp, BDIM*BDIM);
  convert_bf16_kernel<<<(HID*BDIM + 255)/256, 256, 0, stream>>>(fc1_w, w1, HID*BDIM);
  convert_bf16_kernel<<<(BDIM*HID + 255)/256, 256, 0, stream>>>(fc2_w, w2, BDIM*HID);

  hipMemsetAsync(kvT, 0, (size_t)BB*HEADS*HD*HD*4, stream);
  hipMemsetAsync(ksum, 0, (size_t)BB*HEADS*HD*4, stream);

  cpe_ln1_kernel<<<MTOT/(4*TPW), 256, 0, stream>>>(x, cpe_w, cpe_b, ln1_w, ln1_b, out, cur);
  gemm_kernel<0><<<dim3(9, MTOT/256), 512, 0, stream>>>(cur, wq, qkv_b, nullptr, big, 1152, BDIM);
  kv_mfma_kernel<<<dim3(BB*HEADS, 7), 256, 0, stream>>>(big, kvT, ksum);
  attn_mfma_kernel<<<dim3(BB*HEADS, 13), 256, 0, stream>>>(big, kvT, ksum, temp, cur);
  gemm_kernel<2><<<dim3(3, MTOT/256), 512, 0, stream>>>(cur, wp, proj_b, out, out, BDIM, BDIM);
  ln_kernel<<<MTOT/(4*TPW), 256, 0, stream>>>(out, ln2_w, ln2_b, cur);
  gemm_kernel<1><<<dim3(12, MTOT/256), 512, 0, stream>>>(cur, w1, fc1_b, nullptr, big, HID, BDIM);
  gemm_kernel<2><<<dim3(3, MTOT/256), 512, 0, stream>>>(big, w2, fc2_b, out, out, BDIM, HID);
}